// Round 2
// baseline (413.028 us; speedup 1.0000x reference)
//
#include <hip/hip_runtime.h>

// Masked mean/var normalization over time axis.
// x: (B=64, F=256, T=4000) fp32, lengths: (B,) fp32.
// For each (b,f): n = rint(lengths[b]*T); mean/var over t<n (var with n-1);
// out[b,f,t] = (x[b,f,t]-mean)/max(sqrt(var),1e-10) for ALL t.
//
// V2: stage the row in LDS instead of registers (prior 425.8us version held
// float4 v[4] live across two barriers -> suspected VGPR occupancy cliff).
// LDS/block = 16 KB + small -> 8 blocks/CU at __launch_bounds__(256,8) ->
// full 32 waves/CU. Nontemporal loads/stores: pure streaming, zero reuse.
//
// V2.1 fix: __builtin_nontemporal_* requires a native vector type, not
// HIP_vector_type<float,4> -> use clang ext_vector_type(4) alias (same
// 16B layout).

#define T_LEN   4000
#define NCHUNK  1000   // float4 chunks per row
#define EPS_STD 1e-10

typedef float fx4 __attribute__((ext_vector_type(4)));

__global__ __launch_bounds__(256, 8) void mvn_kernel(
        const float* __restrict__ x,
        const float* __restrict__ lengths,
        float* __restrict__ out)
{
    __shared__ fx4 srow[NCHUNK];           // 16000 B row stage
    __shared__ double red_s[4], red_q[4];
    __shared__ float  sh_mean, sh_istd;

    const int row = blockIdx.x;            // row = b*F + f  (F=256)
    const int b   = row >> 8;
    const fx4* __restrict__ xr4 = (const fx4*)(x   + (size_t)row * T_LEN);
    fx4* __restrict__       or4 = (fx4*)      (out + (size_t)row * T_LEN);

    const int tid = threadIdx.x;

    // n = round-half-even(lengths[b] * T), matches jnp.round
    const float nf = rintf(lengths[b] * (float)T_LEN);
    const int   n  = (int)nf;              // in [2000, 4000]

    // ---- phase 1: stream row -> LDS, masked partial sums in registers ----
    float s = 0.f, sq = 0.f;
    #pragma unroll
    for (int k = 0; k < 4; ++k) {
        const int c = tid + (k << 8);      // chunk index
        if (c < NCHUNK) {
            const fx4 v = __builtin_nontemporal_load(xr4 + c);
            srow[c] = v;
            const int t0 = c << 2;
            if (t0 + 3 < n) {              // fully inside mask (common case)
                s  += v.x + v.y + v.z + v.w;
                sq += v.x*v.x + v.y*v.y + v.z*v.z + v.w*v.w;
            } else if (t0 < n) {           // straddles the boundary
                if (t0 + 0 < n) { s += v.x; sq += v.x*v.x; }
                if (t0 + 1 < n) { s += v.y; sq += v.y*v.y; }
                if (t0 + 2 < n) { s += v.z; sq += v.z*v.z; }
                if (t0 + 3 < n) { s += v.w; sq += v.w*v.w; }
            }
        }
    }

    // ---- block reduction: wave64 shfl in fp64, then LDS across 4 waves ----
    double ds = (double)s, dq = (double)sq;
    #pragma unroll
    for (int off = 32; off > 0; off >>= 1) {
        ds += __shfl_down(ds, off, 64);
        dq += __shfl_down(dq, off, 64);
    }

    const int wave = tid >> 6;
    const int lane = tid & 63;
    if (lane == 0) { red_s[wave] = ds; red_q[wave] = dq; }
    __syncthreads();

    if (tid == 0) {
        const double tot_s = red_s[0] + red_s[1] + red_s[2] + red_s[3];
        const double tot_q = red_q[0] + red_q[1] + red_q[2] + red_q[3];
        const double dn    = (double)nf;
        const double mean  = tot_s / dn;
        double var = (tot_q - dn * mean * mean) / (dn - 1.0);
        if (var < 0.0) var = 0.0;
        double std = sqrt(var);
        if (std < EPS_STD) std = EPS_STD;
        sh_mean = (float)mean;
        sh_istd = (float)(1.0 / std);
    }
    __syncthreads();

    const float mean = sh_mean;
    const float istd = sh_istd;

    // ---- phase 2: normalize from LDS, nontemporal store ----
    #pragma unroll
    for (int k = 0; k < 4; ++k) {
        const int c = tid + (k << 8);
        if (c < NCHUNK) {
            const fx4 v = srow[c];
            fx4 o;
            o.x = (v.x - mean) * istd;
            o.y = (v.y - mean) * istd;
            o.z = (v.z - mean) * istd;
            o.w = (v.w - mean) * istd;
            __builtin_nontemporal_store(o, or4 + c);
        }
    }
}

extern "C" void kernel_launch(void* const* d_in, const int* in_sizes, int n_in,
                              void* d_out, int out_size, void* d_ws, size_t ws_size,
                              hipStream_t stream) {
    const float* x       = (const float*)d_in[0];
    const float* lengths = (const float*)d_in[1];
    float* out           = (float*)d_out;

    const int B = 64, F = 256;
    const int rows = B * F;                 // 16384 blocks
    mvn_kernel<<<rows, 256, 0, stream>>>(x, lengths, out);
}

// Round 3
// 411.353 us; speedup vs baseline: 1.0041x; 1.0041x over previous
//
#include <hip/hip_runtime.h>

// Masked mean/var normalization over time axis.
// x: (B=64, F=256, T=4000) fp32, lengths: (B,) fp32.
// For each (b,f): n = rint(lengths[b]*T); mean/var over t<n (var with n-1);
// out[b,f,t] = (x[b,f,t]-mean)/max(sqrt(var),1e-10) for ALL t.
//
// V3: rocprof showed top-5 dispatches are all 159us poison fills -> the
// kernel itself is <159us (~94us inferred: 413 total - ~319 fill). Remaining
// gap to the 83us copy-roofline attacked by:
//  - drop the LDS row-stage entirely (phase 2 reads exactly the chunks this
//    thread loaded -> registers suffice, v[4] = 16 VGPRs, no LDS traffic)
//  - ONE __syncthreads instead of two: all threads redundantly compute the
//    fp64 epilogue from the 4 wave-partials (identical results), removing
//    the tid==0 serialization + second barrier's vmcnt drain.
// Nontemporal load/store: pure streaming, zero reuse.

#define T_LEN   4000
#define NCHUNK  1000   // float4 chunks per row
#define EPS_STD 1e-10

typedef float fx4 __attribute__((ext_vector_type(4)));

__global__ __launch_bounds__(256, 8) void mvn_kernel(
        const float* __restrict__ x,
        const float* __restrict__ lengths,
        float* __restrict__ out)
{
    __shared__ double red_s[4], red_q[4];

    const int row = blockIdx.x;            // row = b*F + f  (F=256)
    const int b   = row >> 8;
    const fx4* __restrict__ xr4 = (const fx4*)(x   + (size_t)row * T_LEN);
    fx4* __restrict__       or4 = (fx4*)      (out + (size_t)row * T_LEN);

    const int tid = threadIdx.x;

    // n = round-half-even(lengths[b] * T), matches jnp.round
    const float nf = rintf(lengths[b] * (float)T_LEN);
    const int   n  = (int)nf;              // in [2000, 4000]

    // ---- phase 1: row -> registers, masked partial sums ----
    fx4 v[4];
    float s = 0.f, sq = 0.f;
    #pragma unroll
    for (int k = 0; k < 4; ++k) {
        const int c = tid + (k << 8);      // chunk index
        if (c < NCHUNK) {
            v[k] = __builtin_nontemporal_load(xr4 + c);
            const int t0 = c << 2;
            if (t0 + 3 < n) {              // fully inside mask (common case)
                s  += v[k].x + v[k].y + v[k].z + v[k].w;
                sq += v[k].x*v[k].x + v[k].y*v[k].y + v[k].z*v[k].z + v[k].w*v[k].w;
            } else if (t0 < n) {           // straddles the boundary
                if (t0 + 0 < n) { s += v[k].x; sq += v[k].x*v[k].x; }
                if (t0 + 1 < n) { s += v[k].y; sq += v[k].y*v[k].y; }
                if (t0 + 2 < n) { s += v[k].z; sq += v[k].z*v[k].z; }
                if (t0 + 3 < n) { s += v[k].w; sq += v[k].w*v[k].w; }
            }
        }
    }

    // ---- block reduction: wave64 shfl in fp64, partials to LDS ----
    double ds = (double)s, dq = (double)sq;
    #pragma unroll
    for (int off = 32; off > 0; off >>= 1) {
        ds += __shfl_down(ds, off, 64);
        dq += __shfl_down(dq, off, 64);
    }

    const int wave = tid >> 6;
    if ((tid & 63) == 0) { red_s[wave] = ds; red_q[wave] = dq; }
    __syncthreads();                       // the ONLY barrier

    // ---- epilogue: every thread computes identical fp64 stats ----
    const double tot_s = red_s[0] + red_s[1] + red_s[2] + red_s[3];
    const double tot_q = red_q[0] + red_q[1] + red_q[2] + red_q[3];
    const double dn    = (double)nf;
    const double meand = tot_s / dn;
    double var = (tot_q - dn * meand * meand) / (dn - 1.0);
    if (var < 0.0) var = 0.0;
    double std = sqrt(var);
    if (std < EPS_STD) std = EPS_STD;
    const float mean = (float)meand;
    const float istd = (float)(1.0 / std);

    // ---- phase 2: normalize from registers, nontemporal store ----
    #pragma unroll
    for (int k = 0; k < 4; ++k) {
        const int c = tid + (k << 8);
        if (c < NCHUNK) {
            fx4 o;
            o.x = (v[k].x - mean) * istd;
            o.y = (v[k].y - mean) * istd;
            o.z = (v[k].z - mean) * istd;
            o.w = (v[k].w - mean) * istd;
            __builtin_nontemporal_store(o, or4 + c);
        }
    }
}

extern "C" void kernel_launch(void* const* d_in, const int* in_sizes, int n_in,
                              void* d_out, int out_size, void* d_ws, size_t ws_size,
                              hipStream_t stream) {
    const float* x       = (const float*)d_in[0];
    const float* lengths = (const float*)d_in[1];
    float* out           = (float*)d_out;

    const int B = 64, F = 256;
    const int rows = B * F;                 // 16384 blocks
    mvn_kernel<<<rows, 256, 0, stream>>>(x, lengths, out);
}